// Round 7
// baseline (254.407 us; speedup 1.0000x reference)
//
#include <hip/hip_runtime.h>

// GraphNN via PATH EXPANSION (matrices AND bias-vectors):
//   T_l = sum_paths (prod inv) P_path;  c_l from bias-path tables (U*/V*/B*);
//   q_l^2 from Q tables (G-dependent, inv-independent).
// Round 18: (a) kLM merged INTO kTab (kTabLM, 184 blocks; 16 ladder blocks
// spin on a done-counter — all blocks co-resident, deadlock-free; counter
// zeroed by kGred each rep). Removes one dispatch boundary AND measures the
// hidden kTab+kLM cost as one kernel. (b) NP=64/16 B=A@G loops register-
// blocked 4x4 with f32x4 LDS reads (~2x fewer LDS instructions).
// 4 dispatches: kGP, kGred, kTabLM, kApply.

#define BF 262144.0f

// ws float offsets
#define OFF_G     0         // 4096
#define OFF_S     4096      // 64
#define OFF_Q1    4160      // 64 (4 used)
#define OFF_Q2    4224      // 64
#define OFF_Q3    4288      // 1024
#define OFF_Q4    5312      // 16384
#define OFF_N2    21696     // 1
#define OFF_DONE  21704     // 1 (u32 done-counter, inside zeroed range)
#define OFF_COUT  21760     // 64
#define OFF_SV1   21824     // 256
#define OFF_SV2   22080     // 1024
#define OFF_SV3   23104     // 4096
#define OFF_SV4   27200     // 16384
#define OFF_MO    43584     // 4096
#define OFF_B0    47680     // 256
#define OFF_B1    47936     // 256
#define OFF_B2    48192     // 256
#define OFF_U2    48512     // 1024
#define OFF_U3    49536     // 4096
#define OFF_U4    53632     // 16384
#define OFF_V3    70016     // 1024
#define OFF_V4A   71040     // 4096
#define OFF_V4B   75136     // 1024
#define OFF_UO    76160     // 16384
#define OFF_VOA   92544     // 4096
#define OFF_VOB   96640     // 1024
#define OFF_VOC   97664     // 256
#define OFF_P2    98304     // 16*4096
#define OFF_P3    163840    // 64*4096
#define OFF_P4    425984    // 256*4096
#define OFF_PO    1474560   // 256*4096
#define OFF_X16   2523136   // bf16 x copy: 16.78M u16
#define NZERO     17600     // floats zeroed from OFF_Q1 (covers Q*, N2, DONE)

typedef __attribute__((ext_vector_type(8))) short bf16x8;
typedef __attribute__((ext_vector_type(4))) float f32x4;
typedef __attribute__((ext_vector_type(4))) unsigned short u16x4;

__device__ __forceinline__ unsigned short f2bf(float f) {
  unsigned u = __builtin_bit_cast(unsigned, f);
  u += 0x7FFF + ((u >> 16) & 1);
  return (unsigned short)(u >> 16);
}

__device__ __forceinline__ bf16x8 cvt8(f32x4 a, f32x4 b, float s) {
  bf16x8 t;
#pragma unroll
  for (int j = 0; j < 4; j++) {
    t[j]     = (short)f2bf(a[j] * s);
    t[j + 4] = (short)f2bf(b[j] * s);
  }
  return t;
}

// ---- LDS 64x64 helpers, stride 68 ----
__device__ __forceinline__ void ld64(float* dst, const float* __restrict__ src, int tid) {
#pragma unroll
  for (int m = 0; m < 4; m++) {
    const int li = m * 1024 + tid * 4;
    *(f32x4*)&dst[(li >> 6) * 68 + (li & 63)] = *(const f32x4*)(src + li);
  }
}
__device__ __forceinline__ void st64(float* __restrict__ dst, const float* src, int tid) {
#pragma unroll
  for (int m = 0; m < 4; m++) {
    const int li = m * 1024 + tid * 4;
    *(f32x4*)(dst + li) = *(const f32x4*)&src[(li >> 6) * 68 + (li & 63)];
  }
}
// C = A @ B (64x64x64, f32, all LDS stride 68)
__device__ __forceinline__ void mm64(float* C, const float* A, const float* B, int tid) {
  const int v0 = (tid >> 4) * 4, w0 = (tid & 15) * 4;
  f32x4 a0 = {0.f,0.f,0.f,0.f}, a1 = a0, a2 = a0, a3 = a0;
#pragma unroll 8
  for (int u = 0; u < 64; u++) {
    const f32x4 b = *(const f32x4*)&B[u * 68 + w0];
    a0 += b * A[(v0 + 0) * 68 + u];
    a1 += b * A[(v0 + 1) * 68 + u];
    a2 += b * A[(v0 + 2) * 68 + u];
    a3 += b * A[(v0 + 3) * 68 + u];
  }
  *(f32x4*)&C[(v0 + 0) * 68 + w0] = a0;
  *(f32x4*)&C[(v0 + 1) * 68 + w0] = a1;
  *(f32x4*)&C[(v0 + 2) * 68 + w0] = a2;
  *(f32x4*)&C[(v0 + 3) * 68 + w0] = a3;
}
// dst[v] = W(LDS,68) @ vec(LDS): quarter-split dot + LDS reduce. 2 syncs.
__device__ __forceinline__ void mv64(float* dst, const float* W, const float* vec,
                                     float (*red)[64], int tid) {
  const int v = tid & 63, q = tid >> 6;
  float p = 0.f;
#pragma unroll
  for (int u = q * 16; u < q * 16 + 16; u++) p += W[v * 68 + u] * vec[u];
  red[q][v] = p;
  __syncthreads();
  if (tid < 64) dst[tid] = red[0][tid] + red[1][tid] + red[2][tid] + red[3][tid];
  __syncthreads();
}

// ---------- kGP: blocks <512 = kG; blocks 512..767 = path chains ------------
__global__ __launch_bounds__(256) void kGP(const float* __restrict__ x,
                                           float* __restrict__ Gpart,
                                           unsigned short* __restrict__ x16,
                                           const float* __restrict__ Win,
                                           const float* __restrict__ bin,
                                           const float* __restrict__ Wmid,
                                           const float* __restrict__ bmid,
                                           const float* __restrict__ Wout,
                                           float* __restrict__ ws) {
  __shared__ __align__(16) char shm[3 * 4352 * 4];
  __shared__ float vbuf[14][64];
  __shared__ float red4v[4][64];
  const int tid = threadIdx.x;

  if (blockIdx.x < 512) {
    typedef unsigned short xts_t[4][16][8];
    xts_t* xts = (xts_t*)shm;
    float (*sred)[4] = (float(*)[4])(shm + 4096);
    const int lane = tid & 63, mt = tid >> 6;
    const int col = lane & 15, q = lane >> 4;
    const int row0 = tid >> 4;
    const int cf0  = (tid & 15) * 4;

    f32x4 acc[4];
#pragma unroll
    for (int nt = 0; nt < 4; nt++) acc[nt] = (f32x4){0.f, 0.f, 0.f, 0.f};
    float s0 = 0.f, s1 = 0.f, s2 = 0.f, s3 = 0.f;

    const long brow = (long)blockIdx.x * 512;
    const float* bx = x + brow * 64;
    f32x4 r0 = *(const f32x4*)(bx + tid * 4);
    f32x4 r1 = *(const f32x4*)(bx + 1024 + tid * 4);

    for (int c = 0; c < 16; c++) {
      __syncthreads();
      s0 += r0[0] + r1[0]; s1 += r0[1] + r1[1];
      s2 += r0[2] + r1[2]; s3 += r0[3] + r1[3];
      u16x4 h0, h1;
#pragma unroll
      for (int j = 0; j < 4; j++) {
        const int cf = cf0 + j;
        const unsigned short b0 = f2bf(r0[j]);
        const unsigned short b1 = f2bf(r1[j]);
        h0[j] = b0; h1[j] = b1;
        xts[cf >> 4][row0 >> 3][cf & 15][row0 & 7]        = b0;
        xts[cf >> 4][2 + (row0 >> 3)][cf & 15][row0 & 7]  = b1;
      }
      *(u16x4*)(x16 + (brow + c * 32 + row0) * 64 + cf0)      = h0;
      *(u16x4*)(x16 + (brow + c * 32 + 16 + row0) * 64 + cf0) = h1;
      f32x4 r0n = r0, r1n = r1;
      if (c < 15) {
        r0n = *(const f32x4*)(bx + (c + 1) * 2048 + tid * 4);
        r1n = *(const f32x4*)(bx + (c + 1) * 2048 + 1024 + tid * 4);
      }
      __syncthreads();
      const bf16x8 af = *(const bf16x8*)xts[mt][q][col];
#pragma unroll
      for (int nt = 0; nt < 4; nt++) {
        const bf16x8 bfr = *(const bf16x8*)xts[nt][q][col];
        acc[nt] = __builtin_amdgcn_mfma_f32_16x16x32_bf16(af, bfr, acc[nt], 0, 0, 0);
      }
      r0 = r0n; r1 = r1n;
    }

    float* myp = Gpart + (long)blockIdx.x * 4160;
#pragma unroll
    for (int nt = 0; nt < 4; nt++)
#pragma unroll
      for (int r = 0; r < 4; r++)
        myp[(mt * 16 + q * 4 + r) * 64 + nt * 16 + col] = acc[nt][r];

    sred[tid][0] = s0; sred[tid][1] = s1; sred[tid][2] = s2; sred[tid][3] = s3;
    __syncthreads();
    if (tid < 64) {
      float t = 0.f;
#pragma unroll
      for (int k2 = 0; k2 < 16; k2++) t += sred[(tid >> 2) + 16 * k2][tid & 3];
      myp[4096 + tid] = t;
    }
  } else {
    float* mb0 = (float*)shm;
    float* mb1 = mb0 + 4352;
    float* mb2 = mb1 + 4352;
    float* binl = vbuf[0]; float* B0l = vbuf[1]; float* B1l = vbuf[2]; float* B2l = vbuf[3];
    float* u2 = vbuf[4];  float* u3 = vbuf[5];  float* v3 = vbuf[6];
    float* u4 = vbuf[7];  float* v4a = vbuf[8]; float* v4b = vbuf[9];
    float* uo = vbuf[10]; float* voa = vbuf[11]; float* vob = vbuf[12]; float* voc = vbuf[13];
    const int pid = blockIdx.x - 512;
    const int p1 = (pid >> 6) & 3, p2 = (pid >> 4) & 3, p3 = (pid >> 2) & 3, p4 = pid & 3;
    const float* bm0 = bmid;
    const float* bm1 = bmid + 1024;
    const float* bm2 = bmid + 2048;

    if (tid < 64) {
      binl[tid] = bin[p1 * 64 + tid];
      B0l[tid] = bm0[(0*4+p2)*64+tid] + bm0[(1*4+p2)*64+tid] + bm0[(2*4+p2)*64+tid] + bm0[(3*4+p2)*64+tid];
      B1l[tid] = bm1[(0*4+p3)*64+tid] + bm1[(1*4+p3)*64+tid] + bm1[(2*4+p3)*64+tid] + bm1[(3*4+p3)*64+tid];
      B2l[tid] = bm2[(0*4+p4)*64+tid] + bm2[(1*4+p4)*64+tid] + bm2[(2*4+p4)*64+tid] + bm2[(3*4+p4)*64+tid];
    }
    ld64(mb0, Win + p1 * 4096, tid);
    ld64(mb1, Wmid + (p1 * 4 + p2) * 4096, tid);
    __syncthreads();
    mv64(u2, mb1, binl, red4v, tid);
    mm64(mb2, mb1, mb0, tid);                                // M2
    __syncthreads();
    if (p3 == 0 && p4 == 0) {
      st64(ws + OFF_P2 + (p1 * 4 + p2) * 4096, mb2, tid);
      if (tid < 64) ws[OFF_U2 + (p1 * 4 + p2) * 64 + tid] = u2[tid];
    }
    ld64(mb1, Wmid + 65536 + (p2 * 4 + p3) * 4096, tid);
    __syncthreads();
    mv64(u3, mb1, u2, red4v, tid);
    mv64(v3, mb1, B0l, red4v, tid);
    mm64(mb0, mb1, mb2, tid);                                // M3
    __syncthreads();
    if (p4 == 0) {
      st64(ws + OFF_P3 + (p1 * 16 + p2 * 4 + p3) * 4096, mb0, tid);
      if (tid < 64) ws[OFF_U3 + (p1 * 16 + p2 * 4 + p3) * 64 + tid] = u3[tid];
      if (p1 == 0 && tid < 64) ws[OFF_V3 + (p2 * 4 + p3) * 64 + tid] = v3[tid];
    }
    ld64(mb1, Wmid + 131072 + (p3 * 4 + p4) * 4096, tid);
    __syncthreads();
    mv64(u4, mb1, u3, red4v, tid);
    mv64(v4a, mb1, v3, red4v, tid);
    mv64(v4b, mb1, B1l, red4v, tid);
    mm64(mb2, mb1, mb0, tid);                                // M4
    __syncthreads();
    st64(ws + OFF_P4 + pid * 4096, mb2, tid);
    if (tid < 64) {
      ws[OFF_U4 + pid * 64 + tid] = u4[tid];
      if (p1 == 0) ws[OFF_V4A + ((p2 * 4 + p3) * 4 + p4) * 64 + tid] = v4a[tid];
      if (p1 == 0 && p2 == 0) ws[OFF_V4B + (p3 * 4 + p4) * 64 + tid] = v4b[tid];
    }
    ld64(mb1, Wout + p4 * 4096, tid);
    __syncthreads();
    mv64(uo, mb1, u4, red4v, tid);
    mv64(voa, mb1, v4a, red4v, tid);
    mv64(vob, mb1, v4b, red4v, tid);
    mv64(voc, mb1, B2l, red4v, tid);
    mm64(mb0, mb1, mb2, tid);                                // PO
    __syncthreads();
    st64(ws + OFF_PO + pid * 4096, mb0, tid);
    if (tid < 64) {
      ws[OFF_UO + pid * 64 + tid] = uo[tid];
      if (p1 == 0) ws[OFF_VOA + ((p2 * 4 + p3) * 4 + p4) * 64 + tid] = voa[tid];
      if (p1 == 0 && p2 == 0) ws[OFF_VOB + (p3 * 4 + p4) * 64 + tid] = vob[tid];
      if (p1 == 0 && p2 == 0 && p3 == 0) ws[OFF_VOC + p4 * 64 + tid] = voc[tid];
    }
    if (pid == 0) {
      const int t = tid >> 6, v = tid & 63;
      ws[OFF_B0 + tid] = bm0[(0*4+t)*64+v] + bm0[(1*4+t)*64+v] + bm0[(2*4+t)*64+v] + bm0[(3*4+t)*64+v];
      ws[OFF_B1 + tid] = bm1[(0*4+t)*64+v] + bm1[(1*4+t)*64+v] + bm1[(2*4+t)*64+v] + bm1[(3*4+t)*64+v];
      ws[OFF_B2 + tid] = bm2[(0*4+t)*64+v] + bm2[(1*4+t)*64+v] + bm2[(2*4+t)*64+v] + bm2[(3*4+t)*64+v];
    }
  }
}

// ---------- kGred: reduce 512 partials -> G, s; zero Q/N2/DONE region -------
__global__ __launch_bounds__(256) void kGred(const float* __restrict__ Gpart,
                                             float* __restrict__ ws) {
  __shared__ float red[4][64];
  const int tid = threadIdx.x;
  for (int i = blockIdx.x * 256 + tid; i < NZERO; i += 65 * 256)
    ws[OFF_Q1 + i] = 0.f;
  const int e = blockIdx.x * 64 + (tid & 63);
  const int quarter = tid >> 6;
  float acc = 0.f;
#pragma unroll 4
  for (int j = 0; j < 128; j++)
    acc += Gpart[(long)(quarter * 128 + j) * 4160 + e];
  red[quarter][tid & 63] = acc;
  __syncthreads();
  if (tid < 64) {
    const float t = red[0][tid] + red[1][tid] + red[2][tid] + red[3][tid];
    const int ee = blockIdx.x * 64 + tid;
    if (ee < 4096) ws[OFF_G + ee] = t;
    else           ws[OFF_S + ee - 4096] = t;
  }
}

// ---------- kTabLM: Q tables + sv (blocks 0..167) | ladder+Mo (168..183) ----
__global__ __launch_bounds__(256) void kTabLM(const float* __restrict__ Win,
                                              const float* __restrict__ bin,
                                              const float* __restrict__ bout,
                                              float* __restrict__ ws) {
  __shared__ __align__(16) char sm[53504];
  const int tid = threadIdx.x, b = blockIdx.x;
  const int it = tid >> 6, lane = tid & 63;

  if (b < 168) {
    // ================= kTab role =================
    float* Gl = (float*)sm;               // 4352
    float* Al = Gl + 4352;                // 4352
    float* Bl = Al + 4352;                // 4352
    float* red = (float*)(sm + 52224);    // 256
    float* sl  = red + 256;               // 64

    ld64(Gl, ws + OFF_G, tid);
    if (tid < 64) sl[tid] = ws[OFF_S + tid];
    __syncthreads();

    if (b < 4) {
      ld64(Al, Win + b * 4096, tid);
      __syncthreads();
      const int vq = it, w = lane;
      float part = 0.f;
      for (int m = 0; m < 16; m++) {
        const int v = vq + m * 4;
        float bw = 0.f;
#pragma unroll 8
        for (int wp = 0; wp < 64; wp++) bw += Al[v * 68 + wp] * Gl[wp * 68 + w];
        part += bw * Al[v * 68 + w];
      }
      red[tid] = part;
      __syncthreads();
      for (int st = 128; st > 0; st >>= 1) {
        if (tid < st) red[tid] += red[tid + st];
        __syncthreads();
      }
      if (tid == 0) ws[OFF_Q1 + b] = red[0];
    } else if (b < 164) {
      int NP, nv, v0, node, qoff;
      const float* Pbase;
      if (b < 20)      { NP = 4;  node = (b - 4)  >> 2; v0 = ((b - 4)  & 3) * 16; nv = 16; Pbase = ws + OFF_P2; qoff = OFF_Q2 + node * 16; }
      else if (b < 36) { NP = 16; node = (b - 20) >> 2; v0 = ((b - 20) & 3) * 16; nv = 16; Pbase = ws + OFF_P3; qoff = OFF_Q3 + node * 256; }
      else             { NP = 64; node = (b - 36) >> 5; v0 = ((b - 36) & 31) * 2; nv = 2;  Pbase = ws + OFF_P4; qoff = OFF_Q4 + node * 4096; }

      float q1acc = 0.f;
      f32x4 qq0 = {0.f,0.f,0.f,0.f}, qq1 = qq0, qq2 = qq0, qq3 = qq0;

      for (int vi = 0; vi < nv; vi++) {
        const int v = v0 + vi;
        __syncthreads();
        for (int e = tid * 4; e < NP * 64; e += 1024) {
          const int j = e >> 6, c = e & 63;
          *(f32x4*)&Al[j * 68 + c] = *(const f32x4*)(Pbase + (long)(j * 4 + node) * 4096 + v * 64 + c);
        }
        __syncthreads();
        // B = A_v @ G
        if (NP == 64) {
          // 4x4 register-blocked, f32x4 on both operands
          const int j0 = (tid >> 4) * 4, w0 = (tid & 15) * 4;
          f32x4 c0 = {0.f,0.f,0.f,0.f}, c1 = c0, c2 = c0, c3 = c0;
#pragma unroll 4
          for (int wp0 = 0; wp0 < 64; wp0 += 4) {
            const f32x4 a0v = *(const f32x4*)&Al[(j0 + 0) * 68 + wp0];
            const f32x4 a1v = *(const f32x4*)&Al[(j0 + 1) * 68 + wp0];
            const f32x4 a2v = *(const f32x4*)&Al[(j0 + 2) * 68 + wp0];
            const f32x4 a3v = *(const f32x4*)&Al[(j0 + 3) * 68 + wp0];
#pragma unroll
            for (int k = 0; k < 4; k++) {
              const f32x4 gv = *(const f32x4*)&Gl[(wp0 + k) * 68 + w0];
              c0 += a0v[k] * gv; c1 += a1v[k] * gv;
              c2 += a2v[k] * gv; c3 += a3v[k] * gv;
            }
          }
          *(f32x4*)&Bl[(j0 + 0) * 68 + w0] = c0;
          *(f32x4*)&Bl[(j0 + 1) * 68 + w0] = c1;
          *(f32x4*)&Bl[(j0 + 2) * 68 + w0] = c2;
          *(f32x4*)&Bl[(j0 + 3) * 68 + w0] = c3;
        } else if (NP == 16) {
          const int j = tid >> 4, w0 = (tid & 15) * 4;
          f32x4 a0 = {0.f,0.f,0.f,0.f};
#pragma unroll 4
          for (int wp0 = 0; wp0 < 64; wp0 += 4) {
            const f32x4 av = *(const f32x4*)&Al[j * 68 + wp0];
#pragma unroll
            for (int k = 0; k < 4; k++)
              a0 += av[k] * *(const f32x4*)&Gl[(wp0 + k) * 68 + w0];
          }
          *(f32x4*)&Bl[j * 68 + w0] = a0;
        } else {
          const int j = tid >> 6, w = tid & 63;
          float a0 = 0.f;
#pragma unroll 8
          for (int wp = 0; wp < 64; wp++) a0 += Al[j * 68 + wp] * Gl[wp * 68 + w];
          Bl[j * 68 + w] = a0;
        }
        __syncthreads();
        // Q += B A^T
        if (NP == 64) {
          const int j0 = (tid >> 4) * 4, jp = tid & 15;
#pragma unroll 4
          for (int w4 = 0; w4 < 16; w4++) {
            const f32x4 b0 = *(const f32x4*)&Bl[(j0 + 0) * 68 + w4 * 4];
            const f32x4 b1 = *(const f32x4*)&Bl[(j0 + 1) * 68 + w4 * 4];
            const f32x4 b2 = *(const f32x4*)&Bl[(j0 + 2) * 68 + w4 * 4];
            const f32x4 b3 = *(const f32x4*)&Bl[(j0 + 3) * 68 + w4 * 4];
#pragma unroll
            for (int bb = 0; bb < 4; bb++) {
              const f32x4 av = *(const f32x4*)&Al[(jp + 16 * bb) * 68 + w4 * 4];
              qq0[bb] += b0[0]*av[0] + b0[1]*av[1] + b0[2]*av[2] + b0[3]*av[3];
              qq1[bb] += b1[0]*av[0] + b1[1]*av[1] + b1[2]*av[2] + b1[3]*av[3];
              qq2[bb] += b2[0]*av[0] + b2[1]*av[1] + b2[2]*av[2] + b2[3]*av[3];
              qq3[bb] += b3[0]*av[0] + b3[1]*av[1] + b3[2]*av[2] + b3[3]*av[3];
            }
          }
        } else if (NP == 16) {
          const int j = tid >> 4, jp = tid & 15;
#pragma unroll 4
          for (int w4 = 0; w4 < 16; w4++) {
            const f32x4 bv = *(const f32x4*)&Bl[j * 68 + w4 * 4];
            const f32x4 av = *(const f32x4*)&Al[jp * 68 + w4 * 4];
            q1acc += bv[0]*av[0] + bv[1]*av[1] + bv[2]*av[2] + bv[3]*av[3];
          }
        } else {
          if (tid < 16) {
            const int j = tid >> 2, jp = tid & 3;
#pragma unroll 8
            for (int w = 0; w < 64; w++) q1acc += Bl[j * 68 + w] * Al[jp * 68 + w];
          }
        }
      }
      if (NP == 64) {
        const int j0 = (tid >> 4) * 4, jp = tid & 15;
#pragma unroll
        for (int bb = 0; bb < 4; bb++) {
          atomicAdd(&ws[qoff + (j0 + 0) * 64 + jp + 16 * bb], qq0[bb]);
          atomicAdd(&ws[qoff + (j0 + 1) * 64 + jp + 16 * bb], qq1[bb]);
          atomicAdd(&ws[qoff + (j0 + 2) * 64 + jp + 16 * bb], qq2[bb]);
          atomicAdd(&ws[qoff + (j0 + 3) * 64 + jp + 16 * bb], qq3[bb]);
        }
      } else if (NP == 16) {
        atomicAdd(&ws[qoff + (tid >> 4) * 16 + (tid & 15)], q1acc);
      } else if (tid < 16) {
        atomicAdd(&ws[qoff + tid], q1acc);
      }
    } else {
      const int vb = b - 164;
      const int lo = vb * 85, hi = (vb == 3) ? 340 : lo + 85;
      for (int vec = lo + it; vec < hi; vec += 4) {
        const float* mat; int dst;
        if (vec < 4)       { mat = Win + vec * 4096;                dst = OFF_SV1 + vec * 64; }
        else if (vec < 20) { mat = ws + OFF_P2 + (vec - 4) * 4096;  dst = OFF_SV2 + (vec - 4) * 64; }
        else if (vec < 84) { mat = ws + OFF_P3 + (vec - 20) * 4096; dst = OFF_SV3 + (vec - 20) * 64; }
        else               { mat = ws + OFF_P4 + (vec - 84) * 4096; dst = OFF_SV4 + (vec - 84) * 64; }
        float acc = 0.f;
#pragma unroll
        for (int u4 = 0; u4 < 16; u4++) {
          const f32x4 mv = *(const f32x4*)(mat + lane * 64 + u4 * 4);
          acc += mv[0]*sl[u4*4] + mv[1]*sl[u4*4+1] + mv[2]*sl[u4*4+2] + mv[3]*sl[u4*4+3];
        }
        ws[dst + lane] = acc;
      }
    }
    // publish completion
    __threadfence();
    __syncthreads();
    if (tid == 0) atomicAdd((unsigned*)&ws[OFF_DONE], 1u);
  } else {
    // ================= kLM role (blocks 168..183) =================
    float* Grow = (float*)sm;                       // 4352 floats
    float* fp   = (float*)(sm + 17408);
    float* binl = fp;        float* c2l = fp + 256;  float* c3l = fp + 512;
    float* c4l  = fp + 768;  float* sv1l = fp + 1024; float* mco = fp + 1280;
    float* redb = fp + 1536; float* sv2l = fp + 1792; // 1024
    float* tfl  = fp + 2816; // 256 ([4][64])
    float* col  = fp + 3072; // 64
    float* sl   = fp + 3136; // 64
    float* inv1 = fp + 3200; float* inv2 = inv1 + 4;
    float* inv3 = inv2 + 4;  float* inv4 = inv3 + 4;
    float* C2l  = fp + 3216; float* C3l = fp + 3220; float* C4l = fp + 3236;
    const int bid = b - 168;

    // pre-loads independent of kTab outputs
    binl[tid] = bin[tid];
    if (tid < 64) sl[tid] = ws[OFF_S + tid];
    ld64(Grow, ws + OFF_G, tid);
    // gate on kTab completion
    if (tid == 0) {
      while (__hip_atomic_load((unsigned*)&ws[OFF_DONE], __ATOMIC_ACQUIRE,
                               __HIP_MEMORY_SCOPE_AGENT) < 168u) {}
    }
    __syncthreads();
    __threadfence();
    sv1l[tid] = ws[OFF_SV1 + tid];
#pragma unroll
    for (int m = 0; m < 4; m++) sv2l[m * 256 + tid] = ws[OFF_SV2 + m * 256 + tid];
    __syncthreads();

    // rung 1
    {
      const float c = binl[it * 64 + lane];
      float part = c * (2.f * sv1l[it * 64 + lane] + BF * c);
#pragma unroll
      for (int off = 32; off; off >>= 1) part += __shfl_down(part, off, 64);
      if (lane == 0) inv1[it] = rsqrtf(ws[OFF_Q1 + it] + part);
    }
    __syncthreads();
    if (tid < 4) C2l[tid] = inv1[tid];
    __syncthreads();
    {
      float acc = ws[OFF_B0 + it * 64 + lane];
#pragma unroll
      for (int p1 = 0; p1 < 4; p1++)
        acc += inv1[p1] * ws[OFF_U2 + (p1 * 4 + it) * 64 + lane];
      c2l[it * 64 + lane] = acc;
    }
    __syncthreads();
    // rung 2
    {
      float ts = 0.f;
#pragma unroll
      for (int p1 = 0; p1 < 4; p1++) ts += C2l[p1] * sv2l[(p1 * 4 + it) * 64 + lane];
      const float c = c2l[it * 64 + lane];
      float part = c * (2.f * ts + BF * c);
      if (lane < 16) part += C2l[lane >> 2] * C2l[lane & 3] * ws[OFF_Q2 + it * 16 + lane];
#pragma unroll
      for (int off = 32; off; off >>= 1) part += __shfl_down(part, off, 64);
      if (lane == 0) inv2[it] = rsqrtf(part);
    }
    __syncthreads();
    if (tid < 16) C3l[tid] = C2l[tid >> 2] * inv2[tid & 3];
    __syncthreads();
    {
      float acc = ws[OFF_B1 + it * 64 + lane];
#pragma unroll
      for (int p2 = 0; p2 < 4; p2++) {
        float tmp = ws[OFF_V3 + (p2 * 4 + it) * 64 + lane];
#pragma unroll
        for (int p1 = 0; p1 < 4; p1++)
          tmp += inv1[p1] * ws[OFF_U3 + ((p1 * 4 + p2) * 4 + it) * 64 + lane];
        acc += inv2[p2] * tmp;
      }
      c3l[it * 64 + lane] = acc;
    }
    __syncthreads();
    // rung 3
    {
      float ts = 0.f;
#pragma unroll
      for (int j = 0; j < 16; j++) ts += C3l[j] * ws[OFF_SV3 + (j * 4 + it) * 64 + lane];
      const float c = c3l[it * 64 + lane];
      float part = c * (2.f * ts + BF * c);
#pragma unroll
      for (int k = 0; k < 4; k++) {
        const int idx = lane * 4 + k;
        part += C3l[idx >> 4] * C3l[idx & 15] * ws[OFF_Q3 + it * 256 + idx];
      }
#pragma unroll
      for (int off = 32; off; off >>= 1) part += __shfl_down(part, off, 64);
      if (lane == 0) inv3[it] = rsqrtf(part);
    }
    __syncthreads();
    if (tid < 64) C4l[tid] = C3l[tid >> 2] * inv3[tid & 3];
    __syncthreads();
    {
      float acc = ws[OFF_B2 + it * 64 + lane];
#pragma unroll
      for (int p3 = 0; p3 < 4; p3++) {
        float t3 = ws[OFF_V4B + (p3 * 4 + it) * 64 + lane];
#pragma unroll
        for (int p2 = 0; p2 < 4; p2++) {
          float t2 = ws[OFF_V4A + ((p2 * 4 + p3) * 4 + it) * 64 + lane];
#pragma unroll
          for (int p1 = 0; p1 < 4; p1++)
            t2 += inv1[p1] * ws[OFF_U4 + (((p1 * 4 + p2) * 4 + p3) * 4 + it) * 64 + lane];
          t3 += inv2[p2] * t2;
        }
        acc += inv3[p3] * t3;
      }
      c4l[it * 64 + lane] = acc;
    }
    __syncthreads();
    // rung 4
    {
      float ts = 0.f;
      for (int j = 0; j < 64; j++) ts += C4l[j] * ws[OFF_SV4 + (j * 4 + it) * 64 + lane];
      const float c = c4l[it * 64 + lane];
      float part = c * (2.f * ts + BF * c);
      float colv = 0.f;
#pragma unroll 8
      for (int j = 0; j < 64; j++)
        colv += C4l[j] * ws[OFF_Q4 + it * 4096 + j * 64 + lane];
      part += C4l[lane] * colv;
#pragma unroll
      for (int off = 32; off; off >>= 1) part += __shfl_down(part, off, 64);
      if (lane == 0) inv4[it] = rsqrtf(part);
    }
    __syncthreads();
    mco[tid] = C4l[tid >> 2] * inv4[tid & 3];
    {
      float acc = ws[OFF_VOC + it * 64 + lane];
#pragma unroll
      for (int p3 = 0; p3 < 4; p3++) {
        float t3 = ws[OFF_VOB + (p3 * 4 + it) * 64 + lane];
#pragma unroll
        for (int p2 = 0; p2 < 4; p2++) {
          float t2 = ws[OFF_VOA + ((p2 * 4 + p3) * 4 + it) * 64 + lane];
#pragma unroll
          for (int p1 = 0; p1 < 4; p1++)
            t2 += inv1[p1] * ws[OFF_UO + (((p1 * 4 + p2) * 4 + p3) * 4 + it) * 64 + lane];
          t3 += inv2[p2] * t2;
        }
        acc += inv3[p3] * t3;
      }
      c2l[it * 64 + lane] = inv4[it] * acc + bout[it * 64 + lane];
    }
    __syncthreads();
    if (tid < 64) col[tid] = c2l[tid] + c2l[64 + tid] + c2l[128 + tid] + c2l[192 + tid];
    __syncthreads();
    if (bid == 0 && tid < 64) ws[OFF_COUT + tid] = col[tid];

    // M phase: Mo rows v = bid*4 + it
    const int v = bid * 4 + it;
    {
      float acc = 0.f;
      const float* po = ws + OFF_PO + v * 64 + lane;
#pragma unroll 4
      for (int i = 0; i < 256; i++) acc += mco[i] * po[(long)i * 4096];
      tfl[it * 64 + lane] = acc;
      ws[OFF_MO + v * 64 + lane] = acc;
    }
    __syncthreads();
    // n2 partial
    {
      float bw = 0.f;
#pragma unroll 8
      for (int wp = 0; wp < 64; wp++) bw += tfl[it * 64 + wp] * Grow[wp * 68 + lane];
      float part = bw * tfl[it * 64 + lane] + 2.f * col[v] * tfl[it * 64 + lane] * sl[lane];
      redb[tid] = part;
      __syncthreads();
      for (int st = 128; st > 0; st >>= 1) {
        if (tid < st) redb[tid] += redb[tid + st];
        __syncthreads();
      }
      if (tid == 0) atomicAdd(&ws[OFF_N2], redb[0]);
      if (bid == 0 && it == 0) {
        float p2_ = BF * col[lane] * col[lane];
#pragma unroll
        for (int off = 32; off; off >>= 1) p2_ += __shfl_down(p2_, off, 64);
        if (lane == 0) atomicAdd(&ws[OFF_N2], p2_);
      }
    }
  }
}

// ---------- kApply: out = (x @ Mo^T + c_out) * rsqrt(n2) --------------------
__global__ __launch_bounds__(256) void kApply(const unsigned short* __restrict__ x16,
                                              const float* __restrict__ MoU,
                                              const float* __restrict__ coU,
                                              const float* __restrict__ n2p,
                                              float* __restrict__ out) {
  const int tid = threadIdx.x, lane = tid & 63, vt = tid >> 6;
  const int col = lane & 15, q = lane >> 4;
  const float inv = rsqrtf(n2p[0]);

  bf16x8 bfr[2];
  const float* mr = MoU + (vt * 16 + col) * 64 + q * 8;
  bfr[0] = cvt8(*(const f32x4*)mr, *(const f32x4*)(mr + 4), inv);
  bfr[1] = cvt8(*(const f32x4*)(mr + 32), *(const f32x4*)(mr + 36), inv);
  const float cf = inv * coU[vt * 16 + col];

  for (int t = 0; t < 16; t++) {
    const int b0 = (blockIdx.x * 16 + t) * 16;
    const unsigned short* xr = x16 + (long)(b0 + col) * 64 + q * 8;
    const bf16x8 a0 = *(const bf16x8*)xr;
    const bf16x8 a1 = *(const bf16x8*)(xr + 32);
    f32x4 acc = (f32x4){0.f, 0.f, 0.f, 0.f};
    acc = __builtin_amdgcn_mfma_f32_16x16x32_bf16(a0, bfr[0], acc, 0, 0, 0);
    acc = __builtin_amdgcn_mfma_f32_16x16x32_bf16(a1, bfr[1], acc, 0, 0, 0);
#pragma unroll
    for (int r = 0; r < 4; r++)
      out[(long)(b0 + q * 4 + r) * 64 + vt * 16 + col] = acc[r] + cf;
  }
}

extern "C" void kernel_launch(void* const* d_in, const int* in_sizes, int n_in,
                              void* d_out, int out_size, void* d_ws, size_t ws_size,
                              hipStream_t stream) {
  const float* x    = (const float*)d_in[0];
  const float* Win  = (const float*)d_in[1];
  const float* bin  = (const float*)d_in[2];
  const float* Wmid = (const float*)d_in[3];
  const float* bmid = (const float*)d_in[4];
  const float* Wout = (const float*)d_in[5];
  const float* bout = (const float*)d_in[6];
  float* out = (float*)d_out;
  float* ws  = (float*)d_ws;
  float* Gpart = out;   // 8.5 MB scratch inside d_out; fully overwritten by kApply
  unsigned short* x16 = (unsigned short*)(ws + OFF_X16);

  kGP   <<<768, 256, 0, stream>>>(x, Gpart, x16, Win, bin, Wmid, bmid, Wout, ws);
  kGred <<<65, 256, 0, stream>>>(Gpart, ws);
  kTabLM<<<184, 256, 0, stream>>>(Win, bin, bout, ws);
  kApply<<<1024, 256, 0, stream>>>(x16, ws + OFF_MO, ws + OFF_COUT, ws + OFF_N2, out);
}